// Round 5
// baseline (41.793 us; speedup 1.0000x reference)
//
#include <hip/hip_runtime.h>
#include <hip/hip_bf16.h>
#include <math.h>

#define LOG2PI 1.8378770664093453f

typedef __attribute__((ext_vector_type(8))) short bf16x8;
typedef __attribute__((ext_vector_type(4))) float f32x4;

__device__ __forceinline__ ushort f2bf(float f) {
    __hip_bfloat16 h = __float2bfloat16(f);
    return *reinterpret_cast<ushort*>(&h);
}

// ws layout (floats): part[2048] | base[128] | counter(1 uint)
//
// Single fused kernel. grid = 256 blocks: tb = bid & 15 (t-chunk of 128),
// sc = bid >> 4 (8 states = 64 sm columns). 256 threads = 4 waves; wave w
// computes t-rows [w*32, w*32+32) x 64 sm cols via 2x4 tiles of
// mfma_f32_16x16x32_bf16, K=128 (k = [x^2 | x] . [iv | -2 mu iv]).
// Last block (device ticket) does the final alpha/logsumexep reduction.
__global__ __launch_bounds__(256) void hmm_fused_kernel(
    const float* __restrict__ X,
    const float* __restrict__ means,
    const float* __restrict__ log_vars,
    const float* __restrict__ weight_logits,
    const float* __restrict__ trans_logits,
    const float* __restrict__ pi_logits,
    float* __restrict__ part,              // [128*16]
    float* __restrict__ base,              // [128]
    unsigned* __restrict__ cnt,
    float* __restrict__ out) {
    // A: [128 t][128 k] bf16, row stride 256B, XOR-swizzled
    // B: [64 n][128 k] bf16 (n = sm-local), row stride 256B, XOR-swizzled
    __shared__ __align__(16) char A_l[128 * 256];
    __shared__ __align__(16) char B_l[64 * 256];
    __shared__ float soff_l[64];
    __shared__ float wred[4][8];
    __shared__ unsigned last_sh;
    __shared__ float fsm[2], fss[2], fam[2], fas[2];

    const int tb = blockIdx.x & 15;
    const int sc = blockIdx.x >> 4;
    const int tid = threadIdx.x;
    const int w  = tid >> 6;
    const int ln = tid & 63;
    const int t0 = tb * 128;

    // ---- stage A: x^2 (k=0..63), x (k=64..127), bf16, swizzled ------------
    {
        const float4* Xv = (const float4*)(X + (size_t)t0 * 64);
        #pragma unroll
        for (int p = 0; p < 8; p++) {
            int g  = p * 256 + tid;        // float4 index in the 128x64 tile
            int r  = g >> 4;               // t row 0..127
            int d4 = g & 15;               // float4 col -> d = d4*4
            float4 x = Xv[g];
            int swz = (r & 7) << 4;
            ushort4 sq = { f2bf(x.x * x.x), f2bf(x.y * x.y),
                           f2bf(x.z * x.z), f2bf(x.w * x.w) };
            ushort4 xl = { f2bf(x.x), f2bf(x.y), f2bf(x.z), f2bf(x.w) };
            *(ushort4*)(A_l + r * 256 + ((d4 * 8) ^ swz)) = sq;
            *(ushort4*)(A_l + r * 256 + ((128 + d4 * 8) ^ swz)) = xl;
        }
    }

    // ---- stage B + soff: wave w handles n = w*16 .. w*16+15, lane = d ------
    for (int i = 0; i < 16; i++) {
        int n  = w * 16 + i;               // sm-local
        int gi = sc * 4096 + n * 64 + ln;  // (s,m,d) flat
        float lv = log_vars[gi];
        float mu = means[gi];
        float iv = expf(-lv);
        float bv = -2.0f * mu * iv;
        int swz = (n & 7) << 4;
        *(ushort*)(B_l + n * 256 + ((ln * 2) ^ swz))       = f2bf(iv);
        *(ushort*)(B_l + n * 256 + ((128 + ln * 2) ^ swz)) = f2bf(bv);
        float a = lv;
        float b = mu * mu * iv;
        #pragma unroll
        for (int o = 32; o > 0; o >>= 1) {
            a += __shfl_xor(a, o, 64);
            b += __shfl_xor(b, o, 64);
        }
        if (ln == 0)
            soff_l[n] = -0.5f * (a + 64.0f * LOG2PI) - 0.5f * b;
    }

    // wave 3 of tb==0 blocks: base[s] = 2047 * logsumexp(trans row)
    if (w == 3 && tb == 0) {
        #pragma unroll
        for (int j = 0; j < 8; j++) {
            int sg = sc * 8 + j;
            const float* tr = trans_logits + sg * 128;
            float v0 = tr[ln], v1 = tr[ln + 64];
            float m = fmaxf(v0, v1);
            #pragma unroll
            for (int o = 32; o > 0; o >>= 1) m = fmaxf(m, __shfl_xor(m, o, 64));
            float sum = expf(v0 - m) + expf(v1 - m);
            #pragma unroll
            for (int o = 32; o > 0; o >>= 1) sum += __shfl_xor(sum, o, 64);
            float L = m + logf(sum);
            float C = (m - L) + logf(sum);
            if (ln == 0) base[sg] = 2047.0f * C;
        }
    }
    __syncthreads();

    // wave 0: fold weight log-softmax into soff (needs all soff written)
    if (tid < 64) {
        float wl = weight_logits[sc * 64 + tid];   // [S][M] flat == sm-local
        float wm = wl;
        #pragma unroll
        for (int o = 1; o < 8; o <<= 1) wm = fmaxf(wm, __shfl_xor(wm, o, 64));
        float we = expf(wl - wm);
        float ws = we;
        #pragma unroll
        for (int o = 1; o < 8; o <<= 1) ws += __shfl_xor(ws, o, 64);
        soff_l[tid] += wl - (wm + logf(ws));
    }

    // ---- MFMA: C[t][n] = A @ B (k-major both sides) ------------------------
    const int lr = ln & 15;                // row (A) / col (B,C)
    const int lg = ln >> 4;                // k-group
    f32x4 acc[2][4];
    #pragma unroll
    for (int rt = 0; rt < 2; rt++)
        #pragma unroll
        for (int ct = 0; ct < 4; ct++) acc[rt][ct] = (f32x4){0.f, 0.f, 0.f, 0.f};

    #pragma unroll
    for (int kk = 0; kk < 4; kk++) {
        const int kb = kk * 64 + lg * 16;  // byte col of this lane's 8 k's
        bf16x8 af[2];
        #pragma unroll
        for (int rt = 0; rt < 2; rt++) {
            int t = w * 32 + rt * 16 + lr;
            af[rt] = *(const bf16x8*)(A_l + t * 256 + (kb ^ ((t & 7) << 4)));
        }
        #pragma unroll
        for (int ct = 0; ct < 4; ct++) {
            int n = ct * 16 + lr;
            bf16x8 bfr = *(const bf16x8*)(B_l + n * 256 + (kb ^ ((n & 7) << 4)));
            acc[0][ct] = __builtin_amdgcn_mfma_f32_16x16x32_bf16(af[0], bfr, acc[0][ct], 0, 0, 0);
            acc[1][ct] = __builtin_amdgcn_mfma_f32_16x16x32_bf16(af[1], bfr, acc[1][ct], 0, 0, 0);
        }
    }
    __syncthreads();   // soff_l complete (wave 0) before epilogue reads

    // ---- epilogue: em = lse over m (8 adjacent cols = 8 adjacent lanes) ----
    // C/D layout: col = ln&15, row = (ln>>4)*4 + r   [m89]
    float so[4];
    #pragma unroll
    for (int ct = 0; ct < 4; ct++) so[ct] = soff_l[ct * 16 + lr];

    float psum[4] = {0.f, 0.f, 0.f, 0.f};
    #pragma unroll
    for (int ct = 0; ct < 4; ct++) {
        #pragma unroll
        for (int rt = 0; rt < 2; rt++) {
            #pragma unroll
            for (int r = 0; r < 4; r++) {
                float v = fmaf(-0.5f, acc[rt][ct][r], so[ct]);
                float mx = v;
                mx = fmaxf(mx, __shfl_xor(mx, 1, 64));
                mx = fmaxf(mx, __shfl_xor(mx, 2, 64));
                mx = fmaxf(mx, __shfl_xor(mx, 4, 64));
                float e = expf(v - mx);
                e += __shfl_xor(e, 1, 64);
                e += __shfl_xor(e, 2, 64);
                e += __shfl_xor(e, 4, 64);
                psum[ct] += mx + logf(e);
            }
        }
    }
    // sum across the 4 row-groups
    #pragma unroll
    for (int ct = 0; ct < 4; ct++) {
        psum[ct] += __shfl_xor(psum[ct], 16, 64);
        psum[ct] += __shfl_xor(psum[ct], 32, 64);
    }
    if ((ln & 7) == 0 && (ln >> 4) == 0) {   // lanes 0 and 8
        #pragma unroll
        for (int ct = 0; ct < 4; ct++)
            wred[w][ct * 2 + (ln >> 3)] = psum[ct];
    }
    __syncthreads();

    if (tid < 8) {
        float v = wred[0][tid] + wred[1][tid] + wred[2][tid] + wred[3][tid];
        part[(sc * 8 + tid) * 16 + tb] = v;
    }

    // ---- ticket: last block performs the final reduction -------------------
    __syncthreads();
    __threadfence();                       // release: part/base -> device
    if (tid == 0) last_sh = atomicAdd(cnt, 1u);
    __syncthreads();

    if (last_sh == 255u) {                 // block-uniform branch
        __threadfence();                   // acquire: invalidate stale caches

        float p = 0.f, alpha = -INFINITY;
        if (tid < 128) {
            p = pi_logits[tid];
            const float4* p4 = (const float4*)(part + tid * 16);
            float4 a0 = p4[0], a1 = p4[1], a2 = p4[2], a3 = p4[3];
            float v = ((a0.x + a0.y) + (a0.z + a0.w))
                    + ((a1.x + a1.y) + (a1.z + a1.w))
                    + ((a2.x + a2.y) + (a2.z + a2.w))
                    + ((a3.x + a3.y) + (a3.z + a3.w));
            alpha = base[tid] + v;         // log_pi added after lsepi known
        }
        // logsumexp of pi over 128 lanes (waves 0,1; waves 2,3 idle-safe)
        float mx = p;
        #pragma unroll
        for (int o = 32; o > 0; o >>= 1) mx = fmaxf(mx, __shfl_xor(mx, o, 64));
        if (ln == 0 && w < 2) fsm[w] = mx;
        __syncthreads();
        float gmx = fmaxf(fsm[0], fsm[1]);
        float e = (tid < 128) ? expf(p - gmx) : 0.f;
        #pragma unroll
        for (int o = 32; o > 0; o >>= 1) e += __shfl_xor(e, o, 64);
        if (ln == 0 && w < 2) fss[w] = e;
        __syncthreads();
        float lsepi = gmx + logf(fss[0] + fss[1]);

        alpha += (p - lsepi);              // -inf for tid>=128 stays -inf

        float m2 = alpha;
        #pragma unroll
        for (int o = 32; o > 0; o >>= 1) m2 = fmaxf(m2, __shfl_xor(m2, o, 64));
        if (ln == 0 && w < 2) fam[w] = m2;
        __syncthreads();
        float g2 = fmaxf(fam[0], fam[1]);
        float e2 = (tid < 128) ? expf(alpha - g2) : 0.f;
        #pragma unroll
        for (int o = 32; o > 0; o >>= 1) e2 += __shfl_xor(e2, o, 64);
        if (ln == 0 && w < 2) fas[w] = e2;
        __syncthreads();
        if (tid == 0) out[0] = g2 + logf(fas[0] + fas[1]);
    }
}

extern "C" void kernel_launch(void* const* d_in, const int* in_sizes, int n_in,
                              void* d_out, int out_size, void* d_ws, size_t ws_size,
                              hipStream_t stream) {
    const float* X      = (const float*)d_in[0];
    const float* pi_l   = (const float*)d_in[1];
    const float* trans  = (const float*)d_in[2];
    const float* weight = (const float*)d_in[3];
    const float* means  = (const float*)d_in[4];
    const float* lvars  = (const float*)d_in[5];
    float* out = (float*)d_out;

    float* ws_part = (float*)d_ws;              // 2048 floats
    float* ws_base = ws_part + 2048;            // 128 floats
    unsigned* ws_cnt = (unsigned*)(ws_base + 128);

    hipMemsetAsync(ws_cnt, 0, sizeof(unsigned), stream);
    hmm_fused_kernel<<<256, 256, 0, stream>>>(X, means, lvars, weight, trans,
                                              pi_l, ws_part, ws_base, ws_cnt, out);
}

// Round 6
// 24.035 us; speedup vs baseline: 1.7388x; 1.7388x over previous
//
#include <hip/hip_runtime.h>
#include <hip/hip_bf16.h>
#include <math.h>

#define LOG2PI 1.8378770664093453f

typedef __attribute__((ext_vector_type(8))) short bf16x8;
typedef __attribute__((ext_vector_type(4))) float f32x4;

__device__ __forceinline__ ushort f2bf(float f) {
    __hip_bfloat16 h = __float2bfloat16(f);
    return *reinterpret_cast<ushort*>(&h);
}

// ws layout (floats): part[128*16] | base[128]

// grid = 256 blocks: tb = bid & 15 (t-chunk of 128), sc = bid >> 4 (8 states
// = 64 sm columns). 256 threads = 4 waves; wave w computes t-rows
// [w*32, w*32+32) x all 64 sm cols via 2x4 tiles of mfma 16x16x32 bf16, K=128.
__global__ __launch_bounds__(256) void emis_mfma_kernel(
    const float* __restrict__ X,
    const float* __restrict__ means,
    const float* __restrict__ log_vars,
    const float* __restrict__ weight_logits,
    const float* __restrict__ trans_logits,
    float* __restrict__ part,              // [128*16]
    float* __restrict__ base) {            // [128]
    // A: [128 t][128 k] bf16, row stride 256B, XOR-swizzled
    // B: [64 n][128 k] bf16 (n = sm-local), row stride 256B, XOR-swizzled
    __shared__ __align__(16) char A_l[128 * 256];
    __shared__ __align__(16) char B_l[64 * 256];
    __shared__ float soff_l[64];
    __shared__ float wred[4][8];

    const int tb = blockIdx.x & 15;
    const int sc = blockIdx.x >> 4;
    const int tid = threadIdx.x;
    const int w  = tid >> 6;
    const int ln = tid & 63;
    const int t0 = tb * 128;

    // ---- stage A: x^2 (k=0..63), x (k=64..127), bf16, swizzled ------------
    {
        const float4* Xv = (const float4*)(X + (size_t)t0 * 64);
        #pragma unroll
        for (int p = 0; p < 8; p++) {
            int g  = p * 256 + tid;        // float4 index in the 128x64 tile
            int r  = g >> 4;               // t row 0..127
            int d4 = g & 15;               // float4 col -> d = d4*4
            float4 x = Xv[g];
            int swz = (r & 7) << 4;
            ushort4 sq = { f2bf(x.x * x.x), f2bf(x.y * x.y),
                           f2bf(x.z * x.z), f2bf(x.w * x.w) };
            ushort4 xl = { f2bf(x.x), f2bf(x.y), f2bf(x.z), f2bf(x.w) };
            *(ushort4*)(A_l + r * 256 + ((d4 * 8) ^ swz)) = sq;
            *(ushort4*)(A_l + r * 256 + ((128 + d4 * 8) ^ swz)) = xl;
        }
    }

    // ---- stage B + soff: wave w handles n = w*16 .. w*16+15, lane = d ------
    // soff[n] = -0.5*( sum_d(lv + mu^2*iv) + 64*log2pi )  (single reduction)
    #pragma unroll
    for (int i = 0; i < 16; i++) {
        int n  = w * 16 + i;               // sm-local
        int gi = sc * 4096 + n * 64 + ln;  // (s,m,d) flat
        float lv = log_vars[gi];
        float mu = means[gi];
        float iv = __expf(-lv);
        float bv = -2.0f * mu * iv;
        int swz = (n & 7) << 4;
        *(ushort*)(B_l + n * 256 + ((ln * 2) ^ swz))       = f2bf(iv);
        *(ushort*)(B_l + n * 256 + ((128 + ln * 2) ^ swz)) = f2bf(bv);
        float c = fmaf(mu * mu, iv, lv);
        #pragma unroll
        for (int o = 32; o > 0; o >>= 1) c += __shfl_xor(c, o, 64);
        if (ln == 0)
            soff_l[n] = -0.5f * (c + 64.0f * LOG2PI);
    }

    // wave 3 of tb==0 blocks: base[s] = 2047 * logsumexp(trans row)
    if (w == 3 && tb == 0) {
        #pragma unroll
        for (int j = 0; j < 8; j++) {
            int sg = sc * 8 + j;
            const float* tr = trans_logits + sg * 128;
            float v0 = tr[ln], v1 = tr[ln + 64];
            float m = fmaxf(v0, v1);
            #pragma unroll
            for (int o = 32; o > 0; o >>= 1) m = fmaxf(m, __shfl_xor(m, o, 64));
            float sum = __expf(v0 - m) + __expf(v1 - m);
            #pragma unroll
            for (int o = 32; o > 0; o >>= 1) sum += __shfl_xor(sum, o, 64);
            float L = m + __logf(sum);
            float C = (m - L) + __logf(sum);
            if (ln == 0) base[sg] = 2047.0f * C;
        }
    }
    __syncthreads();

    // wave 0: fold weight log-softmax into soff (needs all soff written)
    if (tid < 64) {
        float wl = weight_logits[sc * 64 + tid];   // [S][M] flat == sm-local
        float wm = wl;
        #pragma unroll
        for (int o = 1; o < 8; o <<= 1) wm = fmaxf(wm, __shfl_xor(wm, o, 64));
        float we = __expf(wl - wm);
        float ws = we;
        #pragma unroll
        for (int o = 1; o < 8; o <<= 1) ws += __shfl_xor(ws, o, 64);
        soff_l[tid] += wl - (wm + __logf(ws));
    }

    // ---- MFMA: C[t][n] = A @ B (k-major both sides) ------------------------
    const int lr = ln & 15;                // row (A) / col (B,C)
    const int lg = ln >> 4;                // k-group
    f32x4 acc[2][4];
    #pragma unroll
    for (int rt = 0; rt < 2; rt++)
        #pragma unroll
        for (int ct = 0; ct < 4; ct++) acc[rt][ct] = (f32x4){0.f, 0.f, 0.f, 0.f};

    #pragma unroll
    for (int kk = 0; kk < 4; kk++) {
        const int kb = kk * 64 + lg * 16;  // byte col of this lane's 8 k's
        bf16x8 af[2];
        #pragma unroll
        for (int rt = 0; rt < 2; rt++) {
            int t = w * 32 + rt * 16 + lr;
            af[rt] = *(const bf16x8*)(A_l + t * 256 + (kb ^ ((t & 7) << 4)));
        }
        #pragma unroll
        for (int ct = 0; ct < 4; ct++) {
            int n = ct * 16 + lr;
            bf16x8 bfr = *(const bf16x8*)(B_l + n * 256 + (kb ^ ((n & 7) << 4)));
            acc[0][ct] = __builtin_amdgcn_mfma_f32_16x16x32_bf16(af[0], bfr, acc[0][ct], 0, 0, 0);
            acc[1][ct] = __builtin_amdgcn_mfma_f32_16x16x32_bf16(af[1], bfr, acc[1][ct], 0, 0, 0);
        }
    }
    __syncthreads();   // soff_l complete (wave 0) before epilogue reads

    // ---- epilogue: em = lse over m (8 adjacent cols = 8 adjacent lanes) ----
    // C/D layout: col = ln&15, row = (ln>>4)*4 + r   [m89]
    float so[4];
    #pragma unroll
    for (int ct = 0; ct < 4; ct++) so[ct] = soff_l[ct * 16 + lr];

    float psum[4] = {0.f, 0.f, 0.f, 0.f};
    #pragma unroll
    for (int ct = 0; ct < 4; ct++) {
        #pragma unroll
        for (int rt = 0; rt < 2; rt++) {
            #pragma unroll
            for (int r = 0; r < 4; r++) {
                float v = fmaf(-0.5f, acc[rt][ct][r], so[ct]);
                float mx = v;
                mx = fmaxf(mx, __shfl_xor(mx, 1, 64));
                mx = fmaxf(mx, __shfl_xor(mx, 2, 64));
                mx = fmaxf(mx, __shfl_xor(mx, 4, 64));
                float e = __expf(v - mx);
                e += __shfl_xor(e, 1, 64);
                e += __shfl_xor(e, 2, 64);
                e += __shfl_xor(e, 4, 64);
                psum[ct] += mx + __logf(e);
            }
        }
    }
    // sum across the 4 row-groups
    #pragma unroll
    for (int ct = 0; ct < 4; ct++) {
        psum[ct] += __shfl_xor(psum[ct], 16, 64);
        psum[ct] += __shfl_xor(psum[ct], 32, 64);
    }
    if ((ln & 7) == 0 && (ln >> 4) == 0) {   // lanes 0 and 8
        #pragma unroll
        for (int ct = 0; ct < 4; ct++)
            wred[w][ct * 2 + (ln >> 3)] = psum[ct];
    }
    __syncthreads();

    if (tid < 8) {
        float v = wred[0][tid] + wred[1][tid] + wred[2][tid] + wred[3][tid];
        part[(sc * 8 + tid) * 16 + tb] = v;
    }
}

// ---- final: log_pi lse + alpha + lse over S (parallel) ---------------------
__global__ void final_kernel(const float* __restrict__ part,
                             const float* __restrict__ base,
                             const float* __restrict__ pi_logits,
                             float* __restrict__ out) {
    __shared__ float smx[2], ssum[2], amx[2], asum[2];
    int tid = threadIdx.x;                // 128 threads, 2 waves
    int wv = tid >> 6, ln = tid & 63;

    float p = pi_logits[tid];
    float mx = p;
    #pragma unroll
    for (int o = 32; o > 0; o >>= 1) mx = fmaxf(mx, __shfl_xor(mx, o, 64));
    if (ln == 0) smx[wv] = mx;
    __syncthreads();
    float gmx = fmaxf(smx[0], smx[1]);
    float e = __expf(p - gmx);
    #pragma unroll
    for (int o = 32; o > 0; o >>= 1) e += __shfl_xor(e, o, 64);
    if (ln == 0) ssum[wv] = e;
    __syncthreads();
    float lsepi = gmx + __logf(ssum[0] + ssum[1]);

    float v = 0.f;
    const float4* p4 = (const float4*)(part + tid * 16);
    #pragma unroll
    for (int j = 0; j < 4; j++) {
        float4 a = p4[j];
        v += ((a.x + a.y) + (a.z + a.w));
    }
    float alpha = (p - lsepi) + base[tid] + v;

    float m2 = alpha;
    #pragma unroll
    for (int o = 32; o > 0; o >>= 1) m2 = fmaxf(m2, __shfl_xor(m2, o, 64));
    if (ln == 0) amx[wv] = m2;
    __syncthreads();
    float g2 = fmaxf(amx[0], amx[1]);
    float e2 = __expf(alpha - g2);
    #pragma unroll
    for (int o = 32; o > 0; o >>= 1) e2 += __shfl_xor(e2, o, 64);
    if (ln == 0) asum[wv] = e2;
    __syncthreads();
    if (tid == 0) out[0] = g2 + __logf(asum[0] + asum[1]);
}

extern "C" void kernel_launch(void* const* d_in, const int* in_sizes, int n_in,
                              void* d_out, int out_size, void* d_ws, size_t ws_size,
                              hipStream_t stream) {
    const float* X      = (const float*)d_in[0];
    const float* pi_l   = (const float*)d_in[1];
    const float* trans  = (const float*)d_in[2];
    const float* weight = (const float*)d_in[3];
    const float* means  = (const float*)d_in[4];
    const float* lvars  = (const float*)d_in[5];
    float* out = (float*)d_out;

    float* ws_part = (float*)d_ws;          // 128*16
    float* ws_base = ws_part + 2048;        // 128

    emis_mfma_kernel<<<256, 256, 0, stream>>>(X, means, lvars, weight, trans,
                                              ws_part, ws_base);
    final_kernel<<<1, 128, 0, stream>>>(ws_part, ws_base, pi_l, out);
}

// Round 7
// 14.977 us; speedup vs baseline: 2.7905x; 1.6048x over previous
//
#include <hip/hip_runtime.h>
#include <hip/hip_bf16.h>
#include <math.h>

#define LOG2PI 1.8378770664093453f

typedef __attribute__((ext_vector_type(8))) short bf16x8;
typedef __attribute__((ext_vector_type(4))) float f32x4;

__device__ __forceinline__ ushort f2bf(float f) {
    __hip_bfloat16 h = __float2bfloat16(f);
    return *reinterpret_cast<ushort*>(&h);
}

// ws layout (floats): part[128*16] | base[128]

// grid = 256 blocks: tb = bid & 15 (t-chunk of 128), sc = bid >> 4 (8 states
// = 64 sm columns). 1024 threads = 16 waves (4/SIMD): wave w = wc*8+wr owns
// C-tile rows [wr*16, wr*16+16) x cols [wc*32, wc*32+32) via 1x2 tiles of
// mfma_f32_16x16x32_bf16, K=128 (k = [x^2 | x] . [iv | -2 mu iv]).
__global__ __launch_bounds__(1024) void emis_mfma_kernel(
    const float* __restrict__ X,
    const float* __restrict__ means,
    const float* __restrict__ log_vars,
    const float* __restrict__ weight_logits,
    const float* __restrict__ trans_logits,
    float* __restrict__ part,              // [128*16]
    float* __restrict__ base) {            // [128]
    // A: [128 t][128 k] bf16, row stride 256B, XOR-swizzled
    // B: [64 n][128 k] bf16 (n = sm-local), row stride 256B, XOR-swizzled
    __shared__ __align__(16) char A_l[128 * 256];
    __shared__ __align__(16) char B_l[64 * 256];
    __shared__ float soff_l[64];
    __shared__ float wred[16][4];

    const int tb = blockIdx.x & 15;
    const int sc = blockIdx.x >> 4;
    const int tid = threadIdx.x;
    const int w  = tid >> 6;               // 0..15
    const int ln = tid & 63;
    const int wr = w & 7;                  // row tile (16 t-rows)
    const int wc = w >> 3;                 // col half (32 cols)
    const int t0 = tb * 128;

    // ---- stage A: x^2 (k=0..63), x (k=64..127), bf16, swizzled ------------
    {
        const float4* Xv = (const float4*)(X + (size_t)t0 * 64);
        #pragma unroll
        for (int p = 0; p < 2; p++) {
            int g  = p * 1024 + tid;       // float4 index in the 128x64 tile
            int r  = g >> 4;               // t row 0..127
            int d4 = g & 15;               // float4 col -> d = d4*4
            float4 x = Xv[g];
            int swz = (r & 7) << 4;
            ushort4 sq = { f2bf(x.x * x.x), f2bf(x.y * x.y),
                           f2bf(x.z * x.z), f2bf(x.w * x.w) };
            ushort4 xl = { f2bf(x.x), f2bf(x.y), f2bf(x.z), f2bf(x.w) };
            *(ushort4*)(A_l + r * 256 + ((d4 * 8) ^ swz)) = sq;
            *(ushort4*)(A_l + r * 256 + ((128 + d4 * 8) ^ swz)) = xl;
        }
    }

    // ---- stage B + soff: wave w handles n = w*4 .. w*4+3, lane = d ---------
    // soff[n] = -0.5*( sum_d(lv + mu^2*iv) + 64*log2pi )
    #pragma unroll
    for (int i = 0; i < 4; i++) {
        int n  = w * 4 + i;                // sm-local
        int gi = sc * 4096 + n * 64 + ln;  // (s,m,d) flat
        float lv = log_vars[gi];
        float mu = means[gi];
        float iv = __expf(-lv);
        float bv = -2.0f * mu * iv;
        int swz = (n & 7) << 4;
        *(ushort*)(B_l + n * 256 + ((ln * 2) ^ swz))       = f2bf(iv);
        *(ushort*)(B_l + n * 256 + ((128 + ln * 2) ^ swz)) = f2bf(bv);
        float c = fmaf(mu * mu, iv, lv);
        #pragma unroll
        for (int o = 32; o > 0; o >>= 1) c += __shfl_xor(c, o, 64);
        if (ln == 0)
            soff_l[n] = -0.5f * (c + 64.0f * LOG2PI);
    }

    // waves 8..15 of tb==0 blocks: base[sg] = 2047 * logsumexp(trans row)
    if (tb == 0 && w >= 8) {
        int sg = sc * 8 + (w - 8);
        const float* tr = trans_logits + sg * 128;
        float v0 = tr[ln], v1 = tr[ln + 64];
        float m = fmaxf(v0, v1);
        #pragma unroll
        for (int o = 32; o > 0; o >>= 1) m = fmaxf(m, __shfl_xor(m, o, 64));
        float sum = __expf(v0 - m) + __expf(v1 - m);
        #pragma unroll
        for (int o = 32; o > 0; o >>= 1) sum += __shfl_xor(sum, o, 64);
        float L = m + __logf(sum);
        float C = (m - L) + __logf(sum);
        if (ln == 0) base[sg] = 2047.0f * C;
    }
    __syncthreads();

    // wave 0: fold weight log-softmax into soff (needs all soff written)
    if (tid < 64) {
        float wl = weight_logits[sc * 64 + tid];   // [S][M] flat == sm-local
        float wm = wl;
        #pragma unroll
        for (int o = 1; o < 8; o <<= 1) wm = fmaxf(wm, __shfl_xor(wm, o, 64));
        float we = __expf(wl - wm);
        float ws = we;
        #pragma unroll
        for (int o = 1; o < 8; o <<= 1) ws += __shfl_xor(ws, o, 64);
        soff_l[tid] += wl - (wm + __logf(ws));
    }

    // ---- MFMA: C[t][n] = A @ B (k-major both sides) ------------------------
    const int lr = ln & 15;                // row (A) / col (B,C)
    const int lg = ln >> 4;                // k-group
    const int n0 = wc * 32;
    f32x4 acc[2];
    #pragma unroll
    for (int ct = 0; ct < 2; ct++) acc[ct] = (f32x4){0.f, 0.f, 0.f, 0.f};

    #pragma unroll
    for (int kk = 0; kk < 4; kk++) {
        const int kb = kk * 64 + lg * 16;  // byte col of this lane's 8 k's
        int t = wr * 16 + lr;
        bf16x8 af = *(const bf16x8*)(A_l + t * 256 + (kb ^ ((t & 7) << 4)));
        #pragma unroll
        for (int ct = 0; ct < 2; ct++) {
            int n = n0 + ct * 16 + lr;
            bf16x8 bfr = *(const bf16x8*)(B_l + n * 256 + (kb ^ ((n & 7) << 4)));
            acc[ct] = __builtin_amdgcn_mfma_f32_16x16x32_bf16(af, bfr, acc[ct], 0, 0, 0);
        }
    }
    __syncthreads();   // soff_l complete (wave 0) before epilogue reads

    // ---- epilogue: em = lse over m (8 adjacent cols = 8 adjacent lanes) ----
    // C/D layout: col = ln&15, row = (ln>>4)*4 + r   [m89]
    float so[2];
    #pragma unroll
    for (int ct = 0; ct < 2; ct++) so[ct] = soff_l[n0 + ct * 16 + lr];

    float psum[2] = {0.f, 0.f};
    #pragma unroll
    for (int ct = 0; ct < 2; ct++) {
        #pragma unroll
        for (int r = 0; r < 4; r++) {
            float v = fmaf(-0.5f, acc[ct][r], so[ct]);
            float mx = v;
            mx = fmaxf(mx, __shfl_xor(mx, 1, 64));
            mx = fmaxf(mx, __shfl_xor(mx, 2, 64));
            mx = fmaxf(mx, __shfl_xor(mx, 4, 64));
            float e = __expf(v - mx);
            e += __shfl_xor(e, 1, 64);
            e += __shfl_xor(e, 2, 64);
            e += __shfl_xor(e, 4, 64);
            psum[ct] += mx + __logf(e);
        }
    }
    // fold the 4 row-groups (lg) -> sum over the wave's 16 t-rows
    #pragma unroll
    for (int ct = 0; ct < 2; ct++) {
        psum[ct] += __shfl_xor(psum[ct], 16, 64);
        psum[ct] += __shfl_xor(psum[ct], 32, 64);
    }
    if ((ln & 7) == 0 && ln < 16) {        // lanes 0 and 8
        #pragma unroll
        for (int ct = 0; ct < 2; ct++)
            wred[w][ct * 2 + (ln >> 3)] = psum[ct];
    }
    __syncthreads();

    if (tid < 8) {                         // sc-local state j = tid
        int wbase = (tid >> 2) * 8;        // wc = j>>2
        int slot  = tid & 3;               // ct*2 + half
        float v = 0.f;
        #pragma unroll
        for (int r = 0; r < 8; r++) v += wred[wbase + r][slot];
        part[(sc * 8 + tid) * 16 + tb] = v;
    }
}

// ---- final: log_pi lse + alpha + lse over S (parallel) ---------------------
__global__ void final_kernel(const float* __restrict__ part,
                             const float* __restrict__ base,
                             const float* __restrict__ pi_logits,
                             float* __restrict__ out) {
    __shared__ float smx[2], ssum[2], amx[2], asum[2];
    int tid = threadIdx.x;                // 128 threads, 2 waves
    int wv = tid >> 6, ln = tid & 63;

    float p = pi_logits[tid];
    float mx = p;
    #pragma unroll
    for (int o = 32; o > 0; o >>= 1) mx = fmaxf(mx, __shfl_xor(mx, o, 64));
    if (ln == 0) smx[wv] = mx;
    __syncthreads();
    float gmx = fmaxf(smx[0], smx[1]);
    float e = __expf(p - gmx);
    #pragma unroll
    for (int o = 32; o > 0; o >>= 1) e += __shfl_xor(e, o, 64);
    if (ln == 0) ssum[wv] = e;
    __syncthreads();
    float lsepi = gmx + __logf(ssum[0] + ssum[1]);

    float v = 0.f;
    const float4* p4 = (const float4*)(part + tid * 16);
    #pragma unroll
    for (int j = 0; j < 4; j++) {
        float4 a = p4[j];
        v += ((a.x + a.y) + (a.z + a.w));
    }
    float alpha = (p - lsepi) + base[tid] + v;

    float m2 = alpha;
    #pragma unroll
    for (int o = 32; o > 0; o >>= 1) m2 = fmaxf(m2, __shfl_xor(m2, o, 64));
    if (ln == 0) amx[wv] = m2;
    __syncthreads();
    float g2 = fmaxf(amx[0], amx[1]);
    float e2 = __expf(alpha - g2);
    #pragma unroll
    for (int o = 32; o > 0; o >>= 1) e2 += __shfl_xor(e2, o, 64);
    if (ln == 0) asum[wv] = e2;
    __syncthreads();
    if (tid == 0) out[0] = g2 + __logf(asum[0] + asum[1]);
}

extern "C" void kernel_launch(void* const* d_in, const int* in_sizes, int n_in,
                              void* d_out, int out_size, void* d_ws, size_t ws_size,
                              hipStream_t stream) {
    const float* X      = (const float*)d_in[0];
    const float* pi_l   = (const float*)d_in[1];
    const float* trans  = (const float*)d_in[2];
    const float* weight = (const float*)d_in[3];
    const float* means  = (const float*)d_in[4];
    const float* lvars  = (const float*)d_in[5];
    float* out = (float*)d_out;

    float* ws_part = (float*)d_ws;          // 128*16
    float* ws_base = ws_part + 2048;        // 128

    emis_mfma_kernel<<<256, 1024, 0, stream>>>(X, means, lvars, weight, trans,
                                               ws_part, ws_base);
    final_kernel<<<1, 128, 0, stream>>>(ws_part, ws_base, pi_l, out);
}